// Round 1
// baseline (1201.324 us; speedup 1.0000x reference)
//
#include <hip/hip_runtime.h>
#include <hip/hip_bf16.h>

typedef __attribute__((ext_vector_type(4))) float  f32x4;
typedef __attribute__((ext_vector_type(4))) short  s16x4;
typedef __attribute__((ext_vector_type(8))) short  s16x8;

#define DEVI static __device__ __forceinline__

constexpr int   BQ    = 4096;   // windows
constexpr int   NTOK  = 49;     // tokens per window
constexpr int   DIMC  = 384;
constexpr int   NH    = 12;
constexpr int   HDIM  = 32;
constexpr float SCALE_ = 0.17677669529663687f; // 32^-0.5

DEVI ushort f2bf(float f) {
  union { float f; unsigned u; } v; v.f = f;
  unsigned r = v.u + 0x7fffu + ((v.u >> 16) & 1u);
  return (ushort)(r >> 16);
}

// ---------------- prep kernels ----------------
__global__ void cast_w_kernel(const float* __restrict__ w, ushort* __restrict__ o, int n) {
  int i = blockIdx.x * 256 + threadIdx.x;
  if (i < n) o[i] = f2bf(w[i]);
}

__global__ void build_bias_kernel(const float* __restrict__ tab, const int* __restrict__ idx,
                                  float* __restrict__ bm) {
  int i = blockIdx.x * 256 + threadIdx.x;
  if (i < NH * NTOK * NTOK) {
    int h = i / (NTOK * NTOK), rc = i % (NTOK * NTOK);
    bm[i] = tab[idx[rc] * NH + h];  // bm[h][r][c] = table[idx[r][c]][h]
  }
}

// ---------------- GEMM: C = A * B^T (+bias), bf16 MFMA ----------------
// A: M x K (fp32 if AF32 else bf16), B: N x K bf16 (row-major, K contiguous)
// EPI 0: fp32 C + bias -> outF[m*384+n]
// EPI 1: QKV scatter: bf16 -> Qb[b][h][49][32], Kb same, Vb[b][h][32][64] (transposed, n-padded)
template<bool AF32, int EPI>
__global__ __launch_bounds__(256) void gemm_bt_kernel(
    const void* __restrict__ Ap, const ushort* __restrict__ Bp,
    const float* __restrict__ bias, float* __restrict__ outF,
    ushort* __restrict__ Qb, ushort* __restrict__ Kb, ushort* __restrict__ Vb,
    int K)
{
  __shared__ ushort As[128][72];
  __shared__ ushort Bs[128][72];
  const int tid  = threadIdx.x;
  const int lane = tid & 63;
  const int wv   = tid >> 6;
  const int wm   = (wv >> 1) * 64, wn = (wv & 1) * 64;
  const int l15  = lane & 15, lg = lane >> 4;
  const int nbase = blockIdx.x * 128;   // N-tile fastest -> co-resident blocks share A panel
  const int mbase = blockIdx.y * 128;

  f32x4 acc[4][4];
  #pragma unroll
  for (int i = 0; i < 4; i++)
    #pragma unroll
    for (int j = 0; j < 4; j++) acc[i][j] = (f32x4){0.f, 0.f, 0.f, 0.f};

  for (int k0 = 0; k0 < K; k0 += 64) {
    if (AF32) {
      const float* A = (const float*)Ap;
      #pragma unroll
      for (int i = 0; i < 8; i++) {
        int v = tid + 256 * i;            // 2048 float4 loads = 128 x 64 fp32
        int row = v >> 4, c4 = (v & 15) << 2;
        f32x4 f = *(const f32x4*)(A + (size_t)(mbase + row) * K + k0 + c4);
        s16x4 hv;
        hv[0] = (short)f2bf(f[0]); hv[1] = (short)f2bf(f[1]);
        hv[2] = (short)f2bf(f[2]); hv[3] = (short)f2bf(f[3]);
        *(s16x4*)&As[row][c4] = hv;
      }
    } else {
      const ushort* A = (const ushort*)Ap;
      #pragma unroll
      for (int i = 0; i < 4; i++) {
        int v = tid + 256 * i;            // 1024 x 16B = 128 x 64 bf16
        int row = v >> 3, c8 = (v & 7) << 3;
        *(s16x8*)&As[row][c8] = *(const s16x8*)(A + (size_t)(mbase + row) * K + k0 + c8);
      }
    }
    #pragma unroll
    for (int i = 0; i < 4; i++) {
      int v = tid + 256 * i;
      int row = v >> 3, c8 = (v & 7) << 3;
      *(s16x8*)&Bs[row][c8] = *(const s16x8*)(Bp + (size_t)(nbase + row) * K + k0 + c8);
    }
    __syncthreads();
    #pragma unroll
    for (int kk = 0; kk < 2; kk++) {
      s16x8 af[4], bf[4];
      #pragma unroll
      for (int t = 0; t < 4; t++) af[t] = *(const s16x8*)&As[wm + t*16 + l15][kk*32 + lg*8];
      #pragma unroll
      for (int t = 0; t < 4; t++) bf[t] = *(const s16x8*)&Bs[wn + t*16 + l15][kk*32 + lg*8];
      #pragma unroll
      for (int mt = 0; mt < 4; mt++)
        #pragma unroll
        for (int nt = 0; nt < 4; nt++)
          acc[mt][nt] = __builtin_amdgcn_mfma_f32_16x16x32_bf16(af[mt], bf[nt], acc[mt][nt], 0, 0, 0);
    }
    __syncthreads();
  }

  if (EPI == 0) {
    #pragma unroll
    for (int mt = 0; mt < 4; mt++)
      #pragma unroll
      for (int nt = 0; nt < 4; nt++) {
        int n = nbase + wn + nt*16 + l15;
        float bv = bias[n];
        #pragma unroll
        for (int r = 0; r < 4; r++) {
          int m = mbase + wm + mt*16 + lg*4 + r;
          outF[(size_t)m * DIMC + n] = acc[mt][nt][r] + bv;
        }
      }
  } else {
    const int which = nbase / DIMC;   // uniform per block (128 | 384)
    #pragma unroll
    for (int mt = 0; mt < 4; mt++)
      #pragma unroll
      for (int r = 0; r < 4; r++) {
        int m = mbase + wm + mt*16 + lg*4 + r;
        int b = m / NTOK, nn = m - b * NTOK;
        #pragma unroll
        for (int nt = 0; nt < 4; nt++) {
          int n = nbase + wn + nt*16 + l15;
          int nm = n - which * DIMC;
          int h = nm >> 5, d = nm & 31;
          ushort val = f2bf(acc[mt][nt][r] + bias[n]);
          if (which == 0)      Qb[(((size_t)b*NH + h)*NTOK + nn)*HDIM + d] = val;
          else if (which == 1) Kb[(((size_t)b*NH + h)*NTOK + nn)*HDIM + d] = val;
          else                 Vb[(((size_t)b*NH + h)*HDIM + d)*64 + nn]  = val; // transposed, padded to 64
        }
      }
  }
}

// ---------------- attention: one block per window, wave handles 3 heads ----------------
__global__ __launch_bounds__(256) void attn_kernel(
    const ushort* __restrict__ Qb, const ushort* __restrict__ Kb,
    const ushort* __restrict__ Vb, const float* __restrict__ bm,
    const float* __restrict__ mask, ushort* __restrict__ Ob)
{
  __shared__ ushort Pl[4][64][72];   // per-wave P buffer, padded
  const int b    = blockIdx.x;
  const int tid  = threadIdx.x;
  const int lane = tid & 63, wv = tid >> 6;
  const int l15  = lane & 15, lg = lane >> 4;
  const int widx = b & 63;           // b % NW
  const float* maskw = mask + (size_t)widx * NTOK * NTOK;

  for (int hi = 0; hi < 3; hi++) {
    const int h = wv * 3 + hi;
    const ushort* Qh = Qb + ((size_t)b*NH + h) * NTOK * HDIM;
    const ushort* Kh = Kb + ((size_t)b*NH + h) * NTOK * HDIM;
    const ushort* Vh = Vb + ((size_t)b*NH + h) * HDIM * 64;
    const float*  bmh = bm + (size_t)h * NTOK * NTOK;

    // Q,K fragments straight from global (row-clamped so reads stay in real data)
    s16x8 qf[4], kf[4];
    #pragma unroll
    for (int t = 0; t < 4; t++) {
      int r = t*16 + l15; r = r > 48 ? 48 : r;
      qf[t] = *(const s16x8*)(Qh + r*HDIM + lg*8);
      kf[t] = *(const s16x8*)(Kh + r*HDIM + lg*8);
    }
    f32x4 s[4][4];
    #pragma unroll
    for (int it = 0; it < 4; it++)
      #pragma unroll
      for (int jt = 0; jt < 4; jt++) s[it][jt] = (f32x4){0.f,0.f,0.f,0.f};
    #pragma unroll
    for (int it = 0; it < 4; it++)
      #pragma unroll
      for (int jt = 0; jt < 4; jt++)
        s[it][jt] = __builtin_amdgcn_mfma_f32_16x16x32_bf16(qf[it], kf[jt], s[it][jt], 0, 0, 0);

    // scale + bias + mask, pad-mask, row max
    float rmax[4][4];
    #pragma unroll
    for (int it = 0; it < 4; it++)
      #pragma unroll
      for (int r = 0; r < 4; r++) rmax[it][r] = -3.0e38f;
    #pragma unroll
    for (int it = 0; it < 4; it++)
      #pragma unroll
      for (int jt = 0; jt < 4; jt++) {
        int c = jt*16 + l15;
        #pragma unroll
        for (int r = 0; r < 4; r++) {
          int rr = it*16 + lg*4 + r;
          float v;
          if (rr < NTOK && c < NTOK)
            v = s[it][jt][r] * SCALE_ + bmh[rr*NTOK + c] + maskw[rr*NTOK + c];
          else
            v = -1.0e30f;
          s[it][jt][r] = v;
          rmax[it][r] = fmaxf(rmax[it][r], v);
        }
      }
    #pragma unroll
    for (int it = 0; it < 4; it++)
      #pragma unroll
      for (int r = 0; r < 4; r++)
        #pragma unroll
        for (int x = 1; x < 16; x <<= 1)
          rmax[it][r] = fmaxf(rmax[it][r], __shfl_xor(rmax[it][r], x));

    float rsum[4][4];
    #pragma unroll
    for (int it = 0; it < 4; it++)
      #pragma unroll
      for (int r = 0; r < 4; r++) rsum[it][r] = 0.f;
    #pragma unroll
    for (int it = 0; it < 4; it++)
      #pragma unroll
      for (int jt = 0; jt < 4; jt++)
        #pragma unroll
        for (int r = 0; r < 4; r++) {
          float e = __expf(s[it][jt][r] - rmax[it][r]);
          s[it][jt][r] = e;
          rsum[it][r] += e;
        }
    #pragma unroll
    for (int it = 0; it < 4; it++)
      #pragma unroll
      for (int r = 0; r < 4; r++)
        #pragma unroll
        for (int x = 1; x < 16; x <<= 1)
          rsum[it][r] += __shfl_xor(rsum[it][r], x);

    // P -> LDS (unnormalized, bf16); row-normalization folded into O store
    #pragma unroll
    for (int it = 0; it < 4; it++)
      #pragma unroll
      for (int jt = 0; jt < 4; jt++)
        #pragma unroll
        for (int r = 0; r < 4; r++)
          Pl[wv][it*16 + lg*4 + r][jt*16 + l15] = f2bf(s[it][jt][r]);

    // V^T fragments from global, zero padded columns in registers (NaN-safe)
    s16x8 vf[2][2];
    #pragma unroll
    for (int nt = 0; nt < 2; nt++)
      #pragma unroll
      for (int kk = 0; kk < 2; kk++) {
        int dd = nt*16 + l15;
        int c0 = kk*32 + lg*8;
        s16x8 t = *(const s16x8*)(Vh + dd*64 + c0);
        #pragma unroll
        for (int e = 0; e < 8; e++) if (c0 + e >= NTOK) t[e] = 0;
        vf[nt][kk] = t;
      }

    f32x4 o[4][2];
    #pragma unroll
    for (int it = 0; it < 4; it++)
      #pragma unroll
      for (int nt = 0; nt < 2; nt++) o[it][nt] = (f32x4){0.f,0.f,0.f,0.f};
    #pragma unroll
    for (int it = 0; it < 4; it++)
      #pragma unroll
      for (int kk = 0; kk < 2; kk++) {
        s16x8 pf = *(const s16x8*)&Pl[wv][it*16 + l15][kk*32 + lg*8];
        #pragma unroll
        for (int nt = 0; nt < 2; nt++)
          o[it][nt] = __builtin_amdgcn_mfma_f32_16x16x32_bf16(pf, vf[nt][kk], o[it][nt], 0, 0, 0);
      }

    #pragma unroll
    for (int it = 0; it < 4; it++)
      #pragma unroll
      for (int r = 0; r < 4; r++) {
        int q = it*16 + lg*4 + r;
        if (q < NTOK) {
          float ri = 1.0f / rsum[it][r];
          #pragma unroll
          for (int nt = 0; nt < 2; nt++)
            Ob[((size_t)b*NTOK + q)*DIMC + h*HDIM + nt*16 + l15] = f2bf(o[it][nt][r] * ri);
        }
      }
  }
}

// ---------------- launch ----------------
extern "C" void kernel_launch(void* const* d_in, const int* in_sizes, int n_in,
                              void* d_out, int out_size, void* d_ws, size_t ws_size,
                              hipStream_t stream)
{
  const float* x      = (const float*)d_in[0];
  const float* mask   = (const float*)d_in[1];
  const float* qkv_w  = (const float*)d_in[2];
  const float* qkv_b  = (const float*)d_in[3];
  const float* proj_w = (const float*)d_in[4];
  const float* proj_b = (const float*)d_in[5];
  const float* rtab   = (const float*)d_in[6];
  const int*   ridx   = (const int*)d_in[7];
  float* out = (float*)d_out;

  char* p = (char*)d_ws;
  auto alloc = [&](size_t bytes) { char* r = p; p += (bytes + 255) & ~(size_t)255; return r; };
  ushort* Qb = (ushort*)alloc((size_t)BQ*NH*NTOK*HDIM*2);   // 154.1 MB
  ushort* Kb = (ushort*)alloc((size_t)BQ*NH*NTOK*HDIM*2);   // 154.1 MB
  ushort* Vb = (ushort*)alloc((size_t)BQ*NH*HDIM*64*2);     // 201.3 MB (transposed, padded)
  ushort* Ob = (ushort*)alloc((size_t)BQ*NTOK*DIMC*2);      // 154.1 MB
  ushort* qw = (ushort*)alloc((size_t)3*DIMC*DIMC*2);
  ushort* pw = (ushort*)alloc((size_t)DIMC*DIMC*2);
  float*  bm = (float*)alloc((size_t)NH*NTOK*NTOK*4);

  cast_w_kernel<<<(3*DIMC*DIMC + 255)/256, 256, 0, stream>>>(qkv_w, qw, 3*DIMC*DIMC);
  cast_w_kernel<<<(DIMC*DIMC + 255)/256, 256, 0, stream>>>(proj_w, pw, DIMC*DIMC);
  build_bias_kernel<<<(NH*NTOK*NTOK + 255)/256, 256, 0, stream>>>(rtab, ridx, bm);

  dim3 gA(9, 1568);   // N-tiles fastest: co-resident blocks share the x panel in L2/L3
  gemm_bt_kernel<true, 1><<<gA, 256, 0, stream>>>(x, qw, qkv_b, nullptr, Qb, Kb, Vb, DIMC);

  attn_kernel<<<BQ, 256, 0, stream>>>(Qb, Kb, Vb, bm, mask, Ob);

  dim3 gC(3, 1568);
  gemm_bt_kernel<false, 0><<<gC, 256, 0, stream>>>(Ob, pw, proj_b, out, nullptr, nullptr, nullptr, DIMC);
}

// Round 2
// 1048.741 us; speedup vs baseline: 1.1455x; 1.1455x over previous
//
#include <hip/hip_runtime.h>
#include <hip/hip_bf16.h>

typedef __attribute__((ext_vector_type(4))) float  f32x4;
typedef __attribute__((ext_vector_type(4))) short  s16x4;
typedef __attribute__((ext_vector_type(8))) short  s16x8;

#define DEVI static __device__ __forceinline__

constexpr int   BQ    = 4096;   // windows
constexpr int   NTOK  = 49;     // tokens per window
constexpr int   DIMC  = 384;
constexpr int   NH    = 12;
constexpr int   HDIM  = 32;
constexpr int   NW    = 64;
constexpr float SCALE_ = 0.17677669529663687f; // 32^-0.5

DEVI ushort f2bf(float f) {
  union { float f; unsigned u; } v; v.f = f;
  unsigned r = v.u + 0x7fffu + ((v.u >> 16) & 1u);
  return (ushort)(r >> 16);
}

// async global->LDS, 16B per lane; LDS dest = wave-uniform base + lane*16
DEVI void async_ld16(const ushort* g, const ushort* l) {
  auto gp = reinterpret_cast<const __attribute__((address_space(1))) unsigned int*>(
      reinterpret_cast<uintptr_t>(g));
  auto lp = reinterpret_cast<__attribute__((address_space(3))) unsigned int*>(
      reinterpret_cast<uintptr_t>(l));
  __builtin_amdgcn_global_load_lds(gp, lp, 16, 0, 0);
}

// ---------------- prep kernels ----------------
__global__ void cast_x_kernel(const float* __restrict__ x, ushort* __restrict__ o, int n8) {
  int i = blockIdx.x * 256 + threadIdx.x;
  const int stride = gridDim.x * 256;
  for (; i < n8; i += stride) {
    f32x4 a = *(const f32x4*)(x + (size_t)i * 8);
    f32x4 b = *(const f32x4*)(x + (size_t)i * 8 + 4);
    s16x8 v;
    v[0] = (short)f2bf(a[0]); v[1] = (short)f2bf(a[1]);
    v[2] = (short)f2bf(a[2]); v[3] = (short)f2bf(a[3]);
    v[4] = (short)f2bf(b[0]); v[5] = (short)f2bf(b[1]);
    v[6] = (short)f2bf(b[2]); v[7] = (short)f2bf(b[3]);
    *(s16x8*)(o + (size_t)i * 8) = v;
  }
}

__global__ void cast_w_kernel(const float* __restrict__ w, ushort* __restrict__ o, int n) {
  int i = blockIdx.x * 256 + threadIdx.x;
  if (i < n) o[i] = f2bf(w[i]);
}

// comb[w][h][r][c] = rel_bias + mask  (one gather in attn instead of two)
__global__ void build_bias2_kernel(const float* __restrict__ tab, const int* __restrict__ idx,
                                   const float* __restrict__ mask, float* __restrict__ comb) {
  int i = blockIdx.x * 256 + threadIdx.x;
  if (i < NW * NH * NTOK * NTOK) {
    int rc = i % (NTOK * NTOK);
    int wh = i / (NTOK * NTOK);
    int h = wh % NH, w = wh / NH;
    comb[i] = tab[idx[rc] * NH + h] + mask[(size_t)w * NTOK * NTOK + rc];
  }
}

// ---------------- GEMM: C = A * B^T (+bias), bf16 MFMA, m97 structure ----------------
// A: M x K bf16, B: N x K bf16. 128x128 tile, BK=64, global_load_lds staging.
// EPI 0: fp32 C + bias -> outF[m*384+n]
// EPI 1: QKV scatter: Q scaled by SCALE_, bf16 -> Qb[b][h][49][32], Kb same,
//        Vb[b][h][32][64] (transposed, col-padded to 64)
template<int EPI>
__global__ __launch_bounds__(256) void gemm_bt_kernel(
    const ushort* __restrict__ Ap, const ushort* __restrict__ Bp,
    const float* __restrict__ bias, float* __restrict__ outF,
    ushort* __restrict__ Qb, ushort* __restrict__ Kb, ushort* __restrict__ Vb,
    int K, int NB)
{
  __shared__ ushort As[128 * 64];
  __shared__ ushort Bs[128 * 64];
  const int tid  = threadIdx.x;
  const int lane = tid & 63;
  const int wv   = tid >> 6;
  const int wm   = (wv >> 1) * 64, wn = (wv & 1) * 64;
  const int l15  = lane & 15, lg = lane >> 4;

  // bijective XCD-chunked swizzle (gridDim.x divisible by 8)
  const int chunk = gridDim.x >> 3;
  const int wgid  = (blockIdx.x & 7) * chunk + (blockIdx.x >> 3);
  const int nbase = (wgid % NB) * 128;
  const int mbase = (wgid / NB) * 128;

  const int srow  = lane >> 3;        // row within 8-row segment
  const int scolb = (lane & 7) * 8;   // bf16 col within 64-col tile

  f32x4 acc[4][4];
  #pragma unroll
  for (int i = 0; i < 4; i++)
    #pragma unroll
    for (int j = 0; j < 4; j++) acc[i][j] = (f32x4){0.f, 0.f, 0.f, 0.f};

  for (int k0 = 0; k0 < K; k0 += 64) {
    #pragma unroll
    for (int i = 0; i < 4; i++) {
      int seg = wv * 4 + i;           // 16 segments of 8 rows x 64 cols
      async_ld16(Ap + (size_t)(mbase + seg * 8 + srow) * K + k0 + scolb, As + seg * 512);
      async_ld16(Bp + (size_t)(nbase + seg * 8 + srow) * K + k0 + scolb, Bs + seg * 512);
    }
    __syncthreads();   // compiler drains vmcnt before s_barrier
    #pragma unroll
    for (int kk = 0; kk < 2; kk++) {
      s16x8 af[4], bfv[4];
      #pragma unroll
      for (int t = 0; t < 4; t++) af[t]  = *(const s16x8*)&As[(wm + t*16 + l15) * 64 + kk*32 + lg*8];
      #pragma unroll
      for (int t = 0; t < 4; t++) bfv[t] = *(const s16x8*)&Bs[(wn + t*16 + l15) * 64 + kk*32 + lg*8];
      #pragma unroll
      for (int mt = 0; mt < 4; mt++)
        #pragma unroll
        for (int nt = 0; nt < 4; nt++)
          acc[mt][nt] = __builtin_amdgcn_mfma_f32_16x16x32_bf16(af[mt], bfv[nt], acc[mt][nt], 0, 0, 0);
    }
    __syncthreads();
  }

  if (EPI == 0) {
    #pragma unroll
    for (int mt = 0; mt < 4; mt++)
      #pragma unroll
      for (int nt = 0; nt < 4; nt++) {
        int n = nbase + wn + nt*16 + l15;
        float bv = bias[n];
        #pragma unroll
        for (int r = 0; r < 4; r++) {
          int m = mbase + wm + mt*16 + lg*4 + r;
          outF[(size_t)m * DIMC + n] = acc[mt][nt][r] + bv;
        }
      }
  } else {
    const int which = nbase / DIMC;   // uniform per block: 0=Q 1=K 2=V
    #pragma unroll
    for (int mt = 0; mt < 4; mt++)
      #pragma unroll
      for (int r = 0; r < 4; r++) {
        int m = mbase + wm + mt*16 + lg*4 + r;
        int b = m / NTOK, nn = m - b * NTOK;
        #pragma unroll
        for (int nt = 0; nt < 4; nt++) {
          int n = nbase + wn + nt*16 + l15;
          int nm = n - which * DIMC;
          int h = nm >> 5, d = nm & 31;
          float v = acc[mt][nt][r] + bias[n];
          if (which == 0) {
            Qb[(((size_t)b*NH + h)*NTOK + nn)*HDIM + d] = f2bf(v * SCALE_);
          } else if (which == 1) {
            Kb[(((size_t)b*NH + h)*NTOK + nn)*HDIM + d] = f2bf(v);
          } else {
            Vb[(((size_t)b*NH + h)*HDIM + d)*64 + nn] = f2bf(v); // transposed, padded to 64
          }
        }
      }
  }
}

// ---------------- attention: one block per window, wave handles 3 heads ----------------
__global__ __launch_bounds__(256) void attn_kernel(
    const ushort* __restrict__ Qb, const ushort* __restrict__ Kb,
    const ushort* __restrict__ Vb, const float* __restrict__ comb,
    ushort* __restrict__ Ob)
{
  __shared__ ushort Pl[4][64][72];   // per-wave P buffer, padded
  const int b    = blockIdx.x;
  const int tid  = threadIdx.x;
  const int lane = tid & 63, wv = tid >> 6;
  const int l15  = lane & 15, lg = lane >> 4;
  const int widx = b & (NW - 1);

  for (int hi = 0; hi < 3; hi++) {
    const int h = wv * 3 + hi;
    const ushort* Qh = Qb + ((size_t)b*NH + h) * NTOK * HDIM;
    const ushort* Kh = Kb + ((size_t)b*NH + h) * NTOK * HDIM;
    const ushort* Vh = Vb + ((size_t)b*NH + h) * HDIM * 64;
    const float*  cw = comb + ((size_t)widx*NH + h) * NTOK * NTOK;

    s16x8 qf[4], kf[4];
    #pragma unroll
    for (int t = 0; t < 4; t++) {
      int r = t*16 + l15; r = r > 48 ? 48 : r;
      qf[t] = *(const s16x8*)(Qh + r*HDIM + lg*8);
      kf[t] = *(const s16x8*)(Kh + r*HDIM + lg*8);
    }
    f32x4 s[4][4];
    #pragma unroll
    for (int it = 0; it < 4; it++)
      #pragma unroll
      for (int jt = 0; jt < 4; jt++) s[it][jt] = (f32x4){0.f,0.f,0.f,0.f};
    #pragma unroll
    for (int it = 0; it < 4; it++)
      #pragma unroll
      for (int jt = 0; jt < 4; jt++)
        s[it][jt] = __builtin_amdgcn_mfma_f32_16x16x32_bf16(qf[it], kf[jt], s[it][jt], 0, 0, 0);

    float rmax[4][4];
    #pragma unroll
    for (int it = 0; it < 4; it++)
      #pragma unroll
      for (int r = 0; r < 4; r++) rmax[it][r] = -3.0e38f;
    #pragma unroll
    for (int it = 0; it < 4; it++)
      #pragma unroll
      for (int jt = 0; jt < 4; jt++) {
        int c = jt*16 + l15;
        #pragma unroll
        for (int r = 0; r < 4; r++) {
          int rr = it*16 + lg*4 + r;
          float v;
          if (rr < NTOK && c < NTOK)
            v = s[it][jt][r] + cw[rr*NTOK + c];
          else
            v = -1.0e30f;
          s[it][jt][r] = v;
          rmax[it][r] = fmaxf(rmax[it][r], v);
        }
      }
    #pragma unroll
    for (int it = 0; it < 4; it++)
      #pragma unroll
      for (int r = 0; r < 4; r++)
        #pragma unroll
        for (int x = 1; x < 16; x <<= 1)
          rmax[it][r] = fmaxf(rmax[it][r], __shfl_xor(rmax[it][r], x));

    float rsum[4][4];
    #pragma unroll
    for (int it = 0; it < 4; it++)
      #pragma unroll
      for (int r = 0; r < 4; r++) rsum[it][r] = 0.f;
    #pragma unroll
    for (int it = 0; it < 4; it++)
      #pragma unroll
      for (int jt = 0; jt < 4; jt++)
        #pragma unroll
        for (int r = 0; r < 4; r++) {
          float e = __expf(s[it][jt][r] - rmax[it][r]);
          s[it][jt][r] = e;
          rsum[it][r] += e;
        }
    #pragma unroll
    for (int it = 0; it < 4; it++)
      #pragma unroll
      for (int r = 0; r < 4; r++)
        #pragma unroll
        for (int x = 1; x < 16; x <<= 1)
          rsum[it][r] += __shfl_xor(rsum[it][r], x);

    // P -> LDS (unnormalized bf16); normalization folded into O store
    #pragma unroll
    for (int it = 0; it < 4; it++)
      #pragma unroll
      for (int jt = 0; jt < 4; jt++)
        #pragma unroll
        for (int r = 0; r < 4; r++)
          Pl[wv][it*16 + lg*4 + r][jt*16 + l15] = f2bf(s[it][jt][r]);

    // V^T fragments; zero padded columns in registers (NaN-safe vs poisoned ws)
    s16x8 vf[2][2];
    #pragma unroll
    for (int nt = 0; nt < 2; nt++)
      #pragma unroll
      for (int kk = 0; kk < 2; kk++) {
        int dd = nt*16 + l15;
        int c0 = kk*32 + lg*8;
        s16x8 t = *(const s16x8*)(Vh + dd*64 + c0);
        #pragma unroll
        for (int e = 0; e < 8; e++) if (c0 + e >= NTOK) t[e] = 0;
        vf[nt][kk] = t;
      }

    f32x4 o[4][2];
    #pragma unroll
    for (int it = 0; it < 4; it++)
      #pragma unroll
      for (int nt = 0; nt < 2; nt++) o[it][nt] = (f32x4){0.f,0.f,0.f,0.f};
    #pragma unroll
    for (int it = 0; it < 4; it++)
      #pragma unroll
      for (int kk = 0; kk < 2; kk++) {
        s16x8 pf = *(const s16x8*)&Pl[wv][it*16 + l15][kk*32 + lg*8];
        #pragma unroll
        for (int nt = 0; nt < 2; nt++)
          o[it][nt] = __builtin_amdgcn_mfma_f32_16x16x32_bf16(pf, vf[nt][kk], o[it][nt], 0, 0, 0);
      }

    #pragma unroll
    for (int it = 0; it < 4; it++)
      #pragma unroll
      for (int r = 0; r < 4; r++) {
        int q = it*16 + lg*4 + r;
        if (q < NTOK) {
          float ri = 1.0f / rsum[it][r];
          #pragma unroll
          for (int nt = 0; nt < 2; nt++)
            Ob[((size_t)b*NTOK + q)*DIMC + h*HDIM + nt*16 + l15] = f2bf(o[it][nt][r] * ri);
        }
      }
  }
}

// ---------------- launch ----------------
extern "C" void kernel_launch(void* const* d_in, const int* in_sizes, int n_in,
                              void* d_out, int out_size, void* d_ws, size_t ws_size,
                              hipStream_t stream)
{
  const float* x      = (const float*)d_in[0];
  const float* mask   = (const float*)d_in[1];
  const float* qkv_w  = (const float*)d_in[2];
  const float* qkv_b  = (const float*)d_in[3];
  const float* proj_w = (const float*)d_in[4];
  const float* proj_b = (const float*)d_in[5];
  const float* rtab   = (const float*)d_in[6];
  const int*   ridx   = (const int*)d_in[7];
  float* out = (float*)d_out;

  char* p = (char*)d_ws;
  auto alloc = [&](size_t bytes) { char* r = p; p += (bytes + 255) & ~(size_t)255; return r; };
  ushort* xb = (ushort*)alloc((size_t)BQ*NTOK*DIMC*2);      // 154.1 MB bf16 x
  ushort* Qb = (ushort*)alloc((size_t)BQ*NH*NTOK*HDIM*2);   // 154.1 MB
  ushort* Kb = (ushort*)alloc((size_t)BQ*NH*NTOK*HDIM*2);   // 154.1 MB
  ushort* Vb = (ushort*)alloc((size_t)BQ*NH*HDIM*64*2);     // 201.3 MB (transposed, padded)
  ushort* Ob = (ushort*)alloc((size_t)BQ*NTOK*DIMC*2);      // 154.1 MB
  ushort* qw = (ushort*)alloc((size_t)3*DIMC*DIMC*2);
  ushort* pw = (ushort*)alloc((size_t)DIMC*DIMC*2);
  float*  cb = (float*)alloc((size_t)NW*NH*NTOK*NTOK*4);    // 7.4 MB combined bias+mask

  const int n8 = BQ*NTOK*DIMC/8;
  cast_x_kernel<<<2048, 256, 0, stream>>>(x, xb, n8);
  cast_w_kernel<<<(3*DIMC*DIMC + 255)/256, 256, 0, stream>>>(qkv_w, qw, 3*DIMC*DIMC);
  cast_w_kernel<<<(DIMC*DIMC + 255)/256, 256, 0, stream>>>(proj_w, pw, DIMC*DIMC);
  build_bias2_kernel<<<(NW*NH*NTOK*NTOK + 255)/256, 256, 0, stream>>>(rtab, ridx, mask, cb);

  // QKV: M=200704, N=1152, K=384 -> 1568*9 = 14112 blocks (div by 8)
  gemm_bt_kernel<1><<<14112, 256, 0, stream>>>(xb, qw, qkv_b, nullptr, Qb, Kb, Vb, DIMC, 9);

  attn_kernel<<<BQ, 256, 0, stream>>>(Qb, Kb, Vb, cb, Ob);

  // proj: M=200704, N=384 -> 1568*3 = 4704 blocks (div by 8)
  gemm_bt_kernel<0><<<4704, 256, 0, stream>>>(Ob, pw, proj_b, out, nullptr, nullptr, nullptr, DIMC, 3);
}

// Round 3
// 925.447 us; speedup vs baseline: 1.2981x; 1.1332x over previous
//
#include <hip/hip_runtime.h>
#include <hip/hip_bf16.h>

typedef __attribute__((ext_vector_type(4))) float  f32x4;
typedef __attribute__((ext_vector_type(4))) short  s16x4;
typedef __attribute__((ext_vector_type(8))) short  s16x8;

#define DEVI static __device__ __forceinline__

constexpr int   BQ    = 4096;   // windows
constexpr int   NTOK  = 49;     // tokens per window
constexpr int   DIMC  = 384;
constexpr int   NH    = 12;
constexpr int   HDIM  = 32;
constexpr int   NW    = 64;
constexpr float SCALE_ = 0.17677669529663687f; // 32^-0.5

DEVI ushort f2bf(float f) {
  union { float f; unsigned u; } v; v.f = f;
  unsigned r = v.u + 0x7fffu + ((v.u >> 16) & 1u);
  return (ushort)(r >> 16);
}

// async global->LDS, 16B per lane; LDS dest = wave-uniform base + lane*16
DEVI void async_ld16(const ushort* g, const ushort* l) {
  auto gp = reinterpret_cast<const __attribute__((address_space(1))) unsigned int*>(
      reinterpret_cast<uintptr_t>(g));
  auto lp = reinterpret_cast<__attribute__((address_space(3))) unsigned int*>(
      reinterpret_cast<uintptr_t>(l));
  __builtin_amdgcn_global_load_lds(gp, lp, 16, 0, 0);
}

// ---------------- prep kernels ----------------
__global__ void cast_x_kernel(const float* __restrict__ x, ushort* __restrict__ o, int n8) {
  int i = blockIdx.x * 256 + threadIdx.x;
  const int stride = gridDim.x * 256;
  for (; i < n8; i += stride) {
    f32x4 a = *(const f32x4*)(x + (size_t)i * 8);
    f32x4 b = *(const f32x4*)(x + (size_t)i * 8 + 4);
    s16x8 v;
    v[0] = (short)f2bf(a[0]); v[1] = (short)f2bf(a[1]);
    v[2] = (short)f2bf(a[2]); v[3] = (short)f2bf(a[3]);
    v[4] = (short)f2bf(b[0]); v[5] = (short)f2bf(b[1]);
    v[6] = (short)f2bf(b[2]); v[7] = (short)f2bf(b[3]);
    *(s16x8*)(o + (size_t)i * 8) = v;
  }
}

__global__ void cast_w_kernel(const float* __restrict__ w, ushort* __restrict__ o, int n) {
  int i = blockIdx.x * 256 + threadIdx.x;
  if (i < n) o[i] = f2bf(w[i]);
}

// comb[w][h][r][c] = rel_bias + mask  (one gather in attn instead of two)
__global__ void build_bias2_kernel(const float* __restrict__ tab, const int* __restrict__ idx,
                                   const float* __restrict__ mask, float* __restrict__ comb) {
  int i = blockIdx.x * 256 + threadIdx.x;
  if (i < NW * NH * NTOK * NTOK) {
    int rc = i % (NTOK * NTOK);
    int wh = i / (NTOK * NTOK);
    int h = wh % NH, w = wh / NH;
    comb[i] = tab[idx[rc] * NH + h] + mask[(size_t)w * NTOK * NTOK + rc];
  }
}

// ---------------- GEMM: C = A * B^T (+bias), bf16 MFMA, m97 structure + T2 swizzle ----
// A: M x K bf16, B: N x K bf16. 128x128 tile, BK=64, global_load_lds staging.
// LDS layout: [128 rows][8 chunks of 16B]; slot (row, c) holds data chunk c ^ (row&7)
// (achieved by pre-swizzling the per-lane GLOBAL source; LDS dest stays linear).
// Read side XORs the chunk index with row&7 -> conflict-free ds_read_b128.
// EPI 0: fp32 C + bias -> outF[m*384+n]
// EPI 1: QKV scatter: Q scaled by SCALE_, bf16 -> Qb[b][h][49][32], Kb same,
//        Vb[b][h][32][64] (transposed, col-padded to 64)
template<int EPI>
__global__ __launch_bounds__(256) void gemm_bt_kernel(
    const ushort* __restrict__ Ap, const ushort* __restrict__ Bp,
    const float* __restrict__ bias, float* __restrict__ outF,
    ushort* __restrict__ Qb, ushort* __restrict__ Kb, ushort* __restrict__ Vb,
    int K, int NB)
{
  __shared__ ushort As[128 * 64];
  __shared__ ushort Bs[128 * 64];
  const int tid  = threadIdx.x;
  const int lane = tid & 63;
  const int wv   = tid >> 6;
  const int wm   = (wv >> 1) * 64, wn = (wv & 1) * 64;
  const int l15  = lane & 15, lg = lane >> 4;

  // bijective XCD-chunked swizzle (gridDim.x divisible by 8)
  const int chunk = gridDim.x >> 3;
  const int wgid  = (blockIdx.x & 7) * chunk + (blockIdx.x >> 3);
  const int nbase = (wgid % NB) * 128;
  const int mbase = (wgid / NB) * 128;

  const int srow  = lane >> 3;                 // row within 8-row segment
  const int scolb = ((lane & 7) ^ srow) * 8;   // PRE-SWIZZLED source chunk (T2)

  f32x4 acc[4][4];
  #pragma unroll
  for (int i = 0; i < 4; i++)
    #pragma unroll
    for (int j = 0; j < 4; j++) acc[i][j] = (f32x4){0.f, 0.f, 0.f, 0.f};

  for (int k0 = 0; k0 < K; k0 += 64) {
    #pragma unroll
    for (int i = 0; i < 4; i++) {
      int seg = wv * 4 + i;           // 16 segments of 8 rows x 64 cols
      async_ld16(Ap + (size_t)(mbase + seg * 8 + srow) * K + k0 + scolb, As + seg * 512);
      async_ld16(Bp + (size_t)(nbase + seg * 8 + srow) * K + k0 + scolb, Bs + seg * 512);
    }
    __syncthreads();   // compiler drains vmcnt before s_barrier
    #pragma unroll
    for (int kk = 0; kk < 2; kk++) {
      s16x8 af[4], bfv[4];
      #pragma unroll
      for (int t = 0; t < 4; t++) {
        int arow = wm + t*16 + l15;
        af[t]  = *(const s16x8*)&As[arow * 64 + (((kk*4 + lg) ^ (arow & 7)) << 3)];
      }
      #pragma unroll
      for (int t = 0; t < 4; t++) {
        int brow = wn + t*16 + l15;
        bfv[t] = *(const s16x8*)&Bs[brow * 64 + (((kk*4 + lg) ^ (brow & 7)) << 3)];
      }
      #pragma unroll
      for (int mt = 0; mt < 4; mt++)
        #pragma unroll
        for (int nt = 0; nt < 4; nt++)
          acc[mt][nt] = __builtin_amdgcn_mfma_f32_16x16x32_bf16(af[mt], bfv[nt], acc[mt][nt], 0, 0, 0);
    }
    __syncthreads();
  }

  if (EPI == 0) {
    #pragma unroll
    for (int mt = 0; mt < 4; mt++)
      #pragma unroll
      for (int nt = 0; nt < 4; nt++) {
        int n = nbase + wn + nt*16 + l15;
        float bv = bias[n];
        #pragma unroll
        for (int r = 0; r < 4; r++) {
          int m = mbase + wm + mt*16 + lg*4 + r;
          outF[(size_t)m * DIMC + n] = acc[mt][nt][r] + bv;
        }
      }
  } else {
    const int which = nbase / DIMC;   // uniform per block: 0=Q 1=K 2=V
    #pragma unroll
    for (int mt = 0; mt < 4; mt++)
      #pragma unroll
      for (int r = 0; r < 4; r++) {
        int m = mbase + wm + mt*16 + lg*4 + r;
        int b = m / NTOK, nn = m - b * NTOK;
        #pragma unroll
        for (int nt = 0; nt < 4; nt++) {
          int n = nbase + wn + nt*16 + l15;
          int nm = n - which * DIMC;
          int h = nm >> 5, d = nm & 31;
          float v = acc[mt][nt][r] + bias[n];
          if (which == 0) {
            Qb[(((size_t)b*NH + h)*NTOK + nn)*HDIM + d] = f2bf(v * SCALE_);
          } else if (which == 1) {
            Kb[(((size_t)b*NH + h)*NTOK + nn)*HDIM + d] = f2bf(v);
          } else {
            Vb[(((size_t)b*NH + h)*HDIM + d)*64 + nn] = f2bf(v); // transposed, padded to 64
          }
        }
      }
  }
}

// ---------------- attention: one block per window, wave handles 3 heads ----------------
__global__ __launch_bounds__(256) void attn_kernel(
    const ushort* __restrict__ Qb, const ushort* __restrict__ Kb,
    const ushort* __restrict__ Vb, const float* __restrict__ comb,
    ushort* __restrict__ Ob)
{
  __shared__ ushort Pl[4][64][72];   // per-wave P buffer, padded
  const int b    = blockIdx.x;
  const int tid  = threadIdx.x;
  const int lane = tid & 63, wv = tid >> 6;
  const int l15  = lane & 15, lg = lane >> 4;
  const int widx = b & (NW - 1);

  for (int hi = 0; hi < 3; hi++) {
    const int h = wv * 3 + hi;
    const ushort* Qh = Qb + ((size_t)b*NH + h) * NTOK * HDIM;
    const ushort* Kh = Kb + ((size_t)b*NH + h) * NTOK * HDIM;
    const ushort* Vh = Vb + ((size_t)b*NH + h) * HDIM * 64;
    const float*  cw = comb + ((size_t)widx*NH + h) * NTOK * NTOK;

    s16x8 qf[4], kf[4];
    #pragma unroll
    for (int t = 0; t < 4; t++) {
      int r = t*16 + l15; r = r > 48 ? 48 : r;
      qf[t] = *(const s16x8*)(Qh + r*HDIM + lg*8);
      kf[t] = *(const s16x8*)(Kh + r*HDIM + lg*8);
    }
    f32x4 s[4][4];
    #pragma unroll
    for (int it = 0; it < 4; it++)
      #pragma unroll
      for (int jt = 0; jt < 4; jt++) s[it][jt] = (f32x4){0.f,0.f,0.f,0.f};
    #pragma unroll
    for (int it = 0; it < 4; it++)
      #pragma unroll
      for (int jt = 0; jt < 4; jt++)
        s[it][jt] = __builtin_amdgcn_mfma_f32_16x16x32_bf16(qf[it], kf[jt], s[it][jt], 0, 0, 0);

    float rmax[4][4];
    #pragma unroll
    for (int it = 0; it < 4; it++)
      #pragma unroll
      for (int r = 0; r < 4; r++) rmax[it][r] = -3.0e38f;
    #pragma unroll
    for (int it = 0; it < 4; it++)
      #pragma unroll
      for (int jt = 0; jt < 4; jt++) {
        int c = jt*16 + l15;
        #pragma unroll
        for (int r = 0; r < 4; r++) {
          int rr = it*16 + lg*4 + r;
          float v;
          if (rr < NTOK && c < NTOK)
            v = s[it][jt][r] + cw[rr*NTOK + c];
          else
            v = -1.0e30f;
          s[it][jt][r] = v;
          rmax[it][r] = fmaxf(rmax[it][r], v);
        }
      }
    #pragma unroll
    for (int it = 0; it < 4; it++)
      #pragma unroll
      for (int r = 0; r < 4; r++)
        #pragma unroll
        for (int x = 1; x < 16; x <<= 1)
          rmax[it][r] = fmaxf(rmax[it][r], __shfl_xor(rmax[it][r], x));

    float rsum[4][4];
    #pragma unroll
    for (int it = 0; it < 4; it++)
      #pragma unroll
      for (int r = 0; r < 4; r++) rsum[it][r] = 0.f;
    #pragma unroll
    for (int it = 0; it < 4; it++)
      #pragma unroll
      for (int jt = 0; jt < 4; jt++)
        #pragma unroll
        for (int r = 0; r < 4; r++) {
          float e = __expf(s[it][jt][r] - rmax[it][r]);
          s[it][jt][r] = e;
          rsum[it][r] += e;
        }
    #pragma unroll
    for (int it = 0; it < 4; it++)
      #pragma unroll
      for (int r = 0; r < 4; r++)
        #pragma unroll
        for (int x = 1; x < 16; x <<= 1)
          rsum[it][r] += __shfl_xor(rsum[it][r], x);

    // P -> LDS (unnormalized bf16); normalization folded into O store
    #pragma unroll
    for (int it = 0; it < 4; it++)
      #pragma unroll
      for (int jt = 0; jt < 4; jt++)
        #pragma unroll
        for (int r = 0; r < 4; r++)
          Pl[wv][it*16 + lg*4 + r][jt*16 + l15] = f2bf(s[it][jt][r]);

    // V^T fragments; zero padded columns in registers (NaN-safe vs poisoned ws)
    s16x8 vf[2][2];
    #pragma unroll
    for (int nt = 0; nt < 2; nt++)
      #pragma unroll
      for (int kk = 0; kk < 2; kk++) {
        int dd = nt*16 + l15;
        int c0 = kk*32 + lg*8;
        s16x8 t = *(const s16x8*)(Vh + dd*64 + c0);
        #pragma unroll
        for (int e = 0; e < 8; e++) if (c0 + e >= NTOK) t[e] = 0;
        vf[nt][kk] = t;
      }

    f32x4 o[4][2];
    #pragma unroll
    for (int it = 0; it < 4; it++)
      #pragma unroll
      for (int nt = 0; nt < 2; nt++) o[it][nt] = (f32x4){0.f,0.f,0.f,0.f};
    #pragma unroll
    for (int it = 0; it < 4; it++)
      #pragma unroll
      for (int kk = 0; kk < 2; kk++) {
        s16x8 pf = *(const s16x8*)&Pl[wv][it*16 + l15][kk*32 + lg*8];
        #pragma unroll
        for (int nt = 0; nt < 2; nt++)
          o[it][nt] = __builtin_amdgcn_mfma_f32_16x16x32_bf16(pf, vf[nt][kk], o[it][nt], 0, 0, 0);
      }

    #pragma unroll
    for (int it = 0; it < 4; it++)
      #pragma unroll
      for (int r = 0; r < 4; r++) {
        int q = it*16 + lg*4 + r;
        if (q < NTOK) {
          float ri = 1.0f / rsum[it][r];
          #pragma unroll
          for (int nt = 0; nt < 2; nt++)
            Ob[((size_t)b*NTOK + q)*DIMC + h*HDIM + nt*16 + l15] = f2bf(o[it][nt][r] * ri);
        }
      }
  }
}

// ---------------- launch ----------------
extern "C" void kernel_launch(void* const* d_in, const int* in_sizes, int n_in,
                              void* d_out, int out_size, void* d_ws, size_t ws_size,
                              hipStream_t stream)
{
  const float* x      = (const float*)d_in[0];
  const float* mask   = (const float*)d_in[1];
  const float* qkv_w  = (const float*)d_in[2];
  const float* qkv_b  = (const float*)d_in[3];
  const float* proj_w = (const float*)d_in[4];
  const float* proj_b = (const float*)d_in[5];
  const float* rtab   = (const float*)d_in[6];
  const int*   ridx   = (const int*)d_in[7];
  float* out = (float*)d_out;

  char* p = (char*)d_ws;
  auto alloc = [&](size_t bytes) { char* r = p; p += (bytes + 255) & ~(size_t)255; return r; };
  ushort* xb = (ushort*)alloc((size_t)BQ*NTOK*DIMC*2);      // 154.1 MB bf16 x
  ushort* Qb = (ushort*)alloc((size_t)BQ*NH*NTOK*HDIM*2);   // 154.1 MB
  ushort* Kb = (ushort*)alloc((size_t)BQ*NH*NTOK*HDIM*2);   // 154.1 MB
  ushort* Vb = (ushort*)alloc((size_t)BQ*NH*HDIM*64*2);     // 201.3 MB (transposed, padded)
  ushort* Ob = (ushort*)alloc((size_t)BQ*NTOK*DIMC*2);      // 154.1 MB
  ushort* qw = (ushort*)alloc((size_t)3*DIMC*DIMC*2);
  ushort* pw = (ushort*)alloc((size_t)DIMC*DIMC*2);
  float*  cb = (float*)alloc((size_t)NW*NH*NTOK*NTOK*4);    // 7.4 MB combined bias+mask

  const int n8 = BQ*NTOK*DIMC/8;
  cast_x_kernel<<<2048, 256, 0, stream>>>(x, xb, n8);
  cast_w_kernel<<<(3*DIMC*DIMC + 255)/256, 256, 0, stream>>>(qkv_w, qw, 3*DIMC*DIMC);
  cast_w_kernel<<<(DIMC*DIMC + 255)/256, 256, 0, stream>>>(proj_w, pw, DIMC*DIMC);
  build_bias2_kernel<<<(NW*NH*NTOK*NTOK + 255)/256, 256, 0, stream>>>(rtab, ridx, mask, cb);

  // QKV: M=200704, N=1152, K=384 -> 1568*9 = 14112 blocks (div by 8)
  gemm_bt_kernel<1><<<14112, 256, 0, stream>>>(xb, qw, qkv_b, nullptr, Qb, Kb, Vb, DIMC, 9);

  attn_kernel<<<BQ, 256, 0, stream>>>(Qb, Kb, Vb, cb, Ob);

  // proj: M=200704, N=384 -> 1568*3 = 4704 blocks (div by 8)
  gemm_bt_kernel<0><<<4704, 256, 0, stream>>>(Ob, pw, proj_b, out, nullptr, nullptr, nullptr, DIMC, 3);
}